// Round 17
// baseline (287.360 us; speedup 1.0000x reference)
//
#include <hip/hip_runtime.h>
#include <hip/hip_fp16.h>
#include <stdint.h>

typedef __attribute__((ext_vector_type(8))) _Float16 f16x8;
typedef __attribute__((ext_vector_type(4))) float f32x4;

#define NIMG 40      // B*T
#define TFR  5
#define CIN  3
#define HH   64
#define WW   64
#define HW   4096
#define PPS  72      // LDS row stride for 64-wide front patch
#define RSTR 72      // om region col stride (halves)
#define CSTR 144     // feat window col stride in BYTES (128 data + 16 pad)

union U32H2 { uint u; __half2 h; };

__device__ __forceinline__ ushort4 f4_to_h4(f32x4 a) {
  ushort4 r;
  r.x = __half_as_ushort(__float2half(a[0]));
  r.y = __half_as_ushort(__float2half(a[1]));
  r.z = __half_as_ushort(__float2half(a[2]));
  r.w = __half_as_ushort(__float2half(a[3]));
  return r;
}
__device__ __forceinline__ void h4_add(f32x4& a, ushort4 s) {
  a[0] += __half2float(__ushort_as_half(s.x));
  a[1] += __half2float(__ushort_as_half(s.y));
  a[2] += __half2float(__ushort_as_half(s.z));
  a[3] += __half2float(__ushort_as_half(s.w));
}

// ---------------- K0: weight prep into MFMA-fragment order ----------------
__global__ __launch_bounds__(256) void k_wprep(
    const float* __restrict__ Wd, const float* __restrict__ Wom,
    const float* __restrict__ Wi, const float* __restrict__ Wo,
    __half* __restrict__ Waf, __half* __restrict__ Womf,
    __half* __restrict__ Wff, __half* __restrict__ Wof)
{
  int idx = blockIdx.x*256 + threadIdx.x;
  if (idx < 36864) {                         // Waf [kg2][tap9][ot4][lane][8]
    int j = idx & 7, lane = (idx >> 3) & 63;
    int grp = idx >> 9;                      // 0..71
    int ot = grp & 3, tg = grp >> 2;         // tg 0..17
    int tap = tg % 9, kg = tg / 9;
    int row = lane & 15, ks = lane >> 4;
    int oc = ot*16 + row;
    int c  = kg*32 + ks*8 + j;
    Waf[idx] = __float2half(Wd[oc*576 + c*9 + tap]);
  } else if (idx < 36864 + 18432) {          // Womf [mt2][k0 18][lane][8]
    int q = idx - 36864;
    int j = q & 7, lane = (q >> 3) & 63;
    int grp = q >> 9;                        // 0..35
    int k0 = grp % 18, mt = grp / 18;
    int row = lane & 15, ks = lane >> 4;
    int oc = mt*16 + row;
    int tap = k0 >> 1;
    int c = (k0 & 1)*32 + ks*8 + j;
    Womf[q] = (oc < 27) ? __float2half(Wom[oc*576 + c*9 + tap]) : __float2half(0.f);
  } else if (idx < 36864 + 18432 + 2048) {   // Wff [wv4][lane][8]
    int q = idx - 36864 - 18432;
    int j = q & 7, lane = (q >> 3) & 63;
    int wv = q >> 9;
    int row = lane & 15, ks = lane >> 4;
    int f = wv*16 + row;
    int kk = ks*8 + j;
    Wff[q] = (kk < 27) ? __float2half(Wi[f*27 + kk]) : __float2half(0.f);
  } else if (idx < 36864 + 18432 + 2048 + 4096) {  // Wof [wv4][half2][lane][8]
    int q = idx - 36864 - 18432 - 2048;
    int j = q & 7, lane = (q >> 3) & 63;
    int grp = q >> 9;                        // 0..7
    int wv = grp >> 1, half = grp & 1;
    int row = lane & 15, ks = lane >> 4;
    int f = wv*16 + row;
    int kk = half*32 + ks*8 + j;
    float v = 0.f;
    if (kk < 27)       v = Wo[f*54 + 27 + kk];
    else if (kk < 54)  v = Wo[f*54 + (kk - 27)];
    Wof[q] = __float2half(v);
  }
}

// ---------------- K1: fused feat + off_feat via MFMA [NHWC fp16 out] ----------------
__global__ __launch_bounds__(256) void k_front(
    const float* __restrict__ x,
    const __half* __restrict__ Wff, const __half* __restrict__ Wof,
    const float* __restrict__ bi, const float* __restrict__ ai,
    const float* __restrict__ bo, const float* __restrict__ aof,
    __half* __restrict__ feat, __half* __restrict__ offf)
{
  __shared__ __align__(16) __half sp[32*PPS];
  int t = threadIdx.x, blk = blockIdx.x;
  int n = blk >> 7;
  int pbase = (blk & 127) * 32;
  int h = pbase >> 6;
  int wbase = pbase & 63;
  int n0 = (n/TFR)*TFR;
  const float* xc = x + (size_t)n*(CIN*HW);
  const float* xr = x + (size_t)n0*(CIN*HW);

  #pragma unroll
  for (int i = 0; i < 8; ++i) {
    int e = i*256 + t;
    int kk = e >> 5, px = e & 31;
    float v = 0.f;
    if (kk < 54) {
      int cur = (kk < 27);
      int kb = cur ? kk : kk - 27;
      int c = kb / 9, k = kb - c*9;
      int y  = h + k/3 - 1;
      int xx = wbase + px + (k - (k/3)*3) - 1;
      if (y >= 0 && y < HH && xx >= 0 && xx < WW)
        v = (cur ? xc : xr)[c*HW + y*WW + xx];
    }
    sp[px*PPS + kk] = __float2half(v);
  }
  __syncthreads();

  int wv = t >> 6, lane = t & 63;
  int row = lane & 15, ks = lane >> 4;
  f16x8 af0 = *(const f16x8*)(Wff + (wv<<9) + lane*8);
  f16x8 aw0 = *(const f16x8*)(Wof + (wv<<10) + lane*8);
  f16x8 aw1 = *(const f16x8*)(Wof + (wv<<10) + 512 + lane*8);
  #pragma unroll
  for (int nt = 0; nt < 2; ++nt) {
    const __half* bp = sp + (nt*16 + row)*PPS + ks*8;
    f16x8 b0 = *(const f16x8*)(bp);
    f16x8 b1 = *(const f16x8*)(bp + 32);
    f32x4 accf = {0.f,0.f,0.f,0.f}, acco = {0.f,0.f,0.f,0.f};
    accf = __builtin_amdgcn_mfma_f32_16x16x32_f16(af0, b0, accf, 0, 0, 0);
    acco = __builtin_amdgcn_mfma_f32_16x16x32_f16(aw0, b0, acco, 0, 0, 0);
    acco = __builtin_amdgcn_mfma_f32_16x16x32_f16(aw1, b1, acco, 0, 0, 0);
    int p  = pbase + nt*16 + row;
    int f0 = wv*16 + ks*4;
    size_t base = ((size_t)n*HW + p)*64 + f0;
    union { ushort4 u; __half b[4]; } pf, po;
    #pragma unroll
    for (int j = 0; j < 4; ++j) {
      float vf = accf[j] + bi[f0+j];
      float aF = ai[f0+j];
      vf = vf >= 0.f ? vf : aF*vf;
      pf.b[j] = __float2half(vf);
      float vo = acco[j] + bo[f0+j];
      float aO = aof[f0+j];
      vo = vo >= 0.f ? vo : aO*vo;
      po.b[j] = __float2half(vo);
    }
    *(ushort4*)(feat + base) = pf.u;
    *(ushort4*)(offf + base) = po.u;
  }
}

// ---------------- K2: persistent fused om+DCN, cross-iteration prefetch ----------------
// Grid = 1024 blocks (4/CU). Each block loops 5 consecutive row-blocks.
// Iter j: region(j)->LDS [issue region(j+1)] -> om -> window(j)->LDS [issue window(j+1)]
//         || params -> gather+MFMA -> merge -> store.
__global__ __launch_bounds__(256, 4) void k_dcn(
    const __half* __restrict__ feat, const __half* __restrict__ offf,
    const __half* __restrict__ Waf, const __half* __restrict__ Womf,
    const float* __restrict__ bom, const float* __restrict__ bd,
    float* __restrict__ out)
{
  __shared__ __align__(16) char smem[5*36*CSTR];  // 25920B: om region, then feat window
  __shared__ __align__(16) char smem2[6912];      // soff(2304)+swgt(4608); later mbuf f16 [32][72]
  __shared__ __half som[27*36];                   // om values, padded stride 36
  __shared__ int sflag;
  ushort4* soff = (ushort4*)smem2;                // [32*9] window-relative byte offsets (u16)
  uint4*   swgt = (uint4*)(smem2 + 2304);         // [32*9] corner weights pre-broadcast half2
  __half*  mbuf = (__half*)smem2;                 // [32 px][72] f16 partials (after P4)

  int t = threadIdx.x;
  int blk = blockIdx.x;
  int xcd = blk & 7, bidx = blk >> 3;             // 8 XCDs x 128 blocks
  int wv = t >> 6, lane = t & 63;
  int row = lane & 15, ks = lane >> 4;
  int nt = wv & 1, kg = wv >> 1;
  int pxl = nt*16 + row;
  int cb = kg*64 + ks*16;
  const __half* afrag = Waf + (kg*9)*2048 + lane*8;
  __half* region = (__half*)smem;
  char* sfeat = smem;

  uint4 rreg[4], wreg[6];

  // ---- prefetch issue helpers (static reg indexing) ----
  auto region_issue = [&](int work_) {
    int n_ = work_ >> 7;
    int pb_ = (work_ & 127) * 32;
    int hr_ = pb_ >> 6, wb_ = pb_ & 63;
    const char* ob_ = (const char*)(offf + (size_t)n_*(HW*64));
    #pragma unroll
    for (int i = 0; i < 4; ++i) {
      int u = i*256 + t;
      uint4 v = make_uint4(0,0,0,0);
      if (u < 816) {
        int ry = u / 272;
        int rem = u - ry*272;
        int rx = rem >> 3, q = rem & 7;
        int y = hr_ + ry - 1, xx = wb_ + rx - 1;
        if ((unsigned)y < 64u && (unsigned)xx < 64u)
          v = *(const uint4*)(ob_ + (((y<<6)+xx)<<7) + q*16);
      }
      rreg[i] = v;
    }
  };
  auto window_issue = [&](int work_) {
    int n_ = work_ >> 7;
    int pb_ = (work_ & 127) * 32;
    int hr_ = pb_ >> 6, wb_ = pb_ & 63;
    const char* fb_ = (const char*)(feat + (size_t)n_*(HW*64));
    #pragma unroll
    for (int i = 0; i < 6; ++i) {
      int u = i*256 + t;
      uint4 v = make_uint4(0,0,0,0);
      if (u < 1440) {
        int r = u / 288;
        int rem = u - r*288;
        int ci = rem >> 3, q = rem & 7;
        int y = hr_ - 2 + r, xx = wb_ - 2 + ci;
        if ((unsigned)y < 64u && (unsigned)xx < 64u)
          v = *(const uint4*)(fb_ + (((y<<6)+xx)<<7) + q*16);
      }
      wreg[i] = v;
    }
  };

  int work = xcd*640 + bidx*5;
  region_issue(work);
  window_issue(work);

  for (int j = 0; j < 5; ++j, ++work) {
    int n = work >> 7;
    int pbase = (work & 127) * 32;
    int hrow = pbase >> 6, wbase = pbase & 63;
    const char* fb = (const char*)(feat + (size_t)n*(HW*64));

    // ---- P0: region regs -> LDS ----
    #pragma unroll
    for (int i = 0; i < 4; ++i) {
      int u = i*256 + t;
      if (u < 816) {
        int ry = u / 272;
        int rem = u - ry*272;
        int rx = rem >> 3, q = rem & 7;
        *(uint4*)((char*)region + ((ry*34 + rx)*RSTR + q*8)*2) = rreg[i];
      }
    }
    __syncthreads();                              // B1: region visible

    // ---- P1: om head (region); issue next region loads; reset flag ----
    if (t == 0) sflag = 1;
    if (j < 4) region_issue(work + 1);
    {
      int mt = wv >> 1, ntp = wv & 1;
      int pxo = ntp*16 + row;
      f32x4 acc = {0.f,0.f,0.f,0.f};
      #pragma unroll
      for (int k0 = 0; k0 < 18; ++k0) {
        int k = k0 >> 1, ky = k/3, kx = k - ky*3;
        int c0 = (k0 & 1)*32;
        f16x8 a = *(const f16x8*)(Womf + ((mt*18 + k0)<<9) + lane*8);
        f16x8 b = *(const f16x8*)(region + (ky*34 + pxo + kx)*RSTR + c0 + ks*8);
        acc = __builtin_amdgcn_mfma_f32_16x16x32_f16(a, b, acc, 0, 0, 0);
      }
      #pragma unroll
      for (int jj = 0; jj < 4; ++jj) {
        int oc = mt*16 + ks*4 + jj;
        if (oc < 27) {
          float r = acc[jj] + bom[oc];
          if (oc >= 18) r = 1.f/(1.f + __expf(-r));
          som[oc*36 + pxo] = __float2half(r);
        }
      }
    }
    __syncthreads();                              // B2: region reads done, som visible

    // ---- P2a: window regs -> LDS (overwrites region); issue next window loads ----
    #pragma unroll
    for (int i = 0; i < 6; ++i) {
      int u = i*256 + t;
      if (u < 1440) {
        int r = u / 288;
        int rem = u - r*288;
        int ci = rem >> 3, q = rem & 7;
        *(uint4*)(sfeat + (r*36 + ci)*CSTR + q*16) = wreg[i];
      }
    }
    if (j < 4) window_issue(work + 1);

    // ---- P2b: params -> soff/swgt + block flag ----
    for (int e = t; e < 32*9; e += 256) {
      int px = e / 9, k = e - px*9;
      int w = wbase + px;
      float dy = __half2float(som[(2*k)*36 + px]);
      float dx = __half2float(som[(2*k+1)*36 + px]);
      float m  = __half2float(som[(18+k)*36 + px]);
      float py = (float)(hrow + (k/3) - 1) + dy;
      float qx = (float)(w + (k - (k/3)*3) - 1) + dx;
      float y0f = floorf(py), x0f = floorf(qx);
      float wy = py - y0f, wx = qx - x0f;
      int y0 = (int)y0f, x0 = (int)x0f;
      int y1 = y0 + 1, x1 = x0 + 1;
      float w00 = (1.f-wy)*(1.f-wx)*m;
      float w01 = (1.f-wy)*wx*m;
      float w10 = wy*(1.f-wx)*m;
      float w11 = wy*wx*m;
      if (y0 < 0 || y0 >= HH) { w00 = 0.f; w01 = 0.f; }
      if (y1 < 0 || y1 >= HH) { w10 = 0.f; w11 = 0.f; }
      if (x0 < 0 || x0 >= WW) { w00 = 0.f; w10 = 0.f; }
      if (x1 < 0 || x1 >= WW) { w01 = 0.f; w11 = 0.f; }
      int y0c = min(max(y0,0),HH-1), y1c = min(max(y1,0),HH-1);
      int x0c = min(max(x0,0),WW-1), x1c = min(max(x1,0),WW-1);
      int yw0 = y0c - (hrow-2), yw1 = y1c - (hrow-2);
      int xw0 = x0c - (wbase-2), xw1 = x1c - (wbase-2);
      bool ok = ((unsigned)yw0 < 5u) & ((unsigned)yw1 < 5u)
              & ((unsigned)xw0 < 36u) & ((unsigned)xw1 < 36u);
      if (!ok) atomicAnd(&sflag, 0);
      int cy0 = min(max(yw0,0),4), cy1 = min(max(yw1,0),4);
      int cx0 = min(max(xw0,0),35), cx1 = min(max(xw1,0),35);
      soff[e] = make_ushort4((ushort)((cy0*36 + cx0)*CSTR), (ushort)((cy0*36 + cx1)*CSTR),
                             (ushort)((cy1*36 + cx0)*CSTR), (ushort)((cy1*36 + cx1)*CSTR));
      U32H2 u00, u01, u10, u11;
      u00.h = __float2half2_rn(w00); u01.h = __float2half2_rn(w01);
      u10.h = __float2half2_rn(w10); u11.h = __float2half2_rn(w11);
      swgt[e] = make_uint4(u00.u, u01.u, u10.u, u11.u);
    }
    __syncthreads();                              // B3: window + params visible

    // ---- P4: 9 taps, K-split gather -> MFMA ----
    f32x4 acc0 = {0.f,0.f,0.f,0.f}, acc1 = {0.f,0.f,0.f,0.f};
    f32x4 acc2 = {0.f,0.f,0.f,0.f}, acc3 = {0.f,0.f,0.f,0.f};
    if (sflag) {
      #pragma unroll
      for (int tap = 0; tap < 9; ++tap) {
        int e = pxl*9 + tap;
        ushort4 off = soff[e];
        uint4 wq  = swgt[e];
        U32H2 W00, W01, W10, W11;
        W00.u = wq.x; W01.u = wq.y; W10.u = wq.z; W11.u = wq.w;
        uint4 c00 = *(const uint4*)(sfeat + (int)off.x + cb);
        uint4 c01 = *(const uint4*)(sfeat + (int)off.y + cb);
        uint4 c10 = *(const uint4*)(sfeat + (int)off.z + cb);
        uint4 c11 = *(const uint4*)(sfeat + (int)off.w + cb);
        uint4 r;
#define BILIN(comp) { U32H2 a0v,a1v,a2v,a3v,res;                                \
        a0v.u = c00.comp; a1v.u = c01.comp; a2v.u = c10.comp; a3v.u = c11.comp; \
        __half2 v = __hmul2(W00.h, a0v.h); v = __hfma2(W01.h, a1v.h, v);        \
        v = __hfma2(W10.h, a2v.h, v);      v = __hfma2(W11.h, a3v.h, v);        \
        res.h = v; r.comp = res.u; }
        BILIN(x) BILIN(y) BILIN(z) BILIN(w)
        f16x8 b = *(f16x8*)&r;
        const __half* ap = afrag + tap*2048;
        f16x8 a0 = *(const f16x8*)(ap);
        f16x8 a1 = *(const f16x8*)(ap + 512);
        f16x8 a2 = *(const f16x8*)(ap + 1024);
        f16x8 a3 = *(const f16x8*)(ap + 1536);
        acc0 = __builtin_amdgcn_mfma_f32_16x16x32_f16(a0, b, acc0, 0, 0, 0);
        acc1 = __builtin_amdgcn_mfma_f32_16x16x32_f16(a1, b, acc1, 0, 0, 0);
        acc2 = __builtin_amdgcn_mfma_f32_16x16x32_f16(a2, b, acc2, 0, 0, 0);
        acc3 = __builtin_amdgcn_mfma_f32_16x16x32_f16(a3, b, acc3, 0, 0, 0);
      }
    } else {
      #pragma unroll 1
      for (int tap = 0; tap < 9; ++tap) {
        float dy = __half2float(som[(2*tap)*36 + pxl]);
        float dx = __half2float(som[(2*tap+1)*36 + pxl]);
        float m  = __half2float(som[(18+tap)*36 + pxl]);
        int ky = tap/3, kx = tap - ky*3;
        float py = (float)(hrow + ky - 1) + dy;
        float qx = (float)(wbase + pxl + kx - 1) + dx;
        float y0f = floorf(py), x0f = floorf(qx);
        float wy = py - y0f, wx = qx - x0f;
        int y0 = (int)y0f, x0 = (int)x0f;
        int y1 = y0 + 1, x1 = x0 + 1;
        float w00 = (1.f-wy)*(1.f-wx)*m;
        float w01 = (1.f-wy)*wx*m;
        float w10 = wy*(1.f-wx)*m;
        float w11 = wy*wx*m;
        if (y0 < 0 || y0 >= HH) { w00 = 0.f; w01 = 0.f; }
        if (y1 < 0 || y1 >= HH) { w10 = 0.f; w11 = 0.f; }
        if (x0 < 0 || x0 >= WW) { w00 = 0.f; w10 = 0.f; }
        if (x1 < 0 || x1 >= WW) { w01 = 0.f; w11 = 0.f; }
        int y0c = min(max(y0,0),HH-1), y1c = min(max(y1,0),HH-1);
        int x0c = min(max(x0,0),WW-1), x1c = min(max(x1,0),WW-1);
        int o00 = (((y0c<<6)+x0c)<<7), o01 = (((y0c<<6)+x1c)<<7);
        int o10 = (((y1c<<6)+x0c)<<7), o11 = (((y1c<<6)+x1c)<<7);
        U32H2 W00, W01, W10, W11;
        W00.h = __float2half2_rn(w00); W01.h = __float2half2_rn(w01);
        W10.h = __float2half2_rn(w10); W11.h = __float2half2_rn(w11);
        uint4 c00 = *(const uint4*)(fb + o00 + cb);
        uint4 c01 = *(const uint4*)(fb + o01 + cb);
        uint4 c10 = *(const uint4*)(fb + o10 + cb);
        uint4 c11 = *(const uint4*)(fb + o11 + cb);
        uint4 r;
        BILIN(x) BILIN(y) BILIN(z) BILIN(w)
#undef BILIN
        f16x8 b = *(f16x8*)&r;
        const __half* ap = afrag + tap*2048;
        f16x8 a0 = *(const f16x8*)(ap);
        f16x8 a1 = *(const f16x8*)(ap + 512);
        f16x8 a2 = *(const f16x8*)(ap + 1024);
        f16x8 a3 = *(const f16x8*)(ap + 1536);
        acc0 = __builtin_amdgcn_mfma_f32_16x16x32_f16(a0, b, acc0, 0, 0, 0);
        acc1 = __builtin_amdgcn_mfma_f32_16x16x32_f16(a1, b, acc1, 0, 0, 0);
        acc2 = __builtin_amdgcn_mfma_f32_16x16x32_f16(a2, b, acc2, 0, 0, 0);
        acc3 = __builtin_amdgcn_mfma_f32_16x16x32_f16(a3, b, acc3, 0, 0, 0);
      }
    }
    __syncthreads();                              // B4: soff/swgt dead; mbuf live

    // ---- P5: merge K-halves (f16 partials), epilogue ----
    if (kg == 1) {
      int mb = pxl*72 + ks*4;
      *(ushort4*)(mbuf + mb)      = f4_to_h4(acc0);
      *(ushort4*)(mbuf + mb + 16) = f4_to_h4(acc1);
      *(ushort4*)(mbuf + mb + 32) = f4_to_h4(acc2);
      *(ushort4*)(mbuf + mb + 48) = f4_to_h4(acc3);
    }
    __syncthreads();                              // B5
    if (kg == 0) {
      int mb = pxl*72 + ks*4;
      h4_add(acc0, *(ushort4*)(mbuf + mb));
      h4_add(acc1, *(ushort4*)(mbuf + mb + 16));
      h4_add(acc2, *(ushort4*)(mbuf + mb + 32));
      h4_add(acc3, *(ushort4*)(mbuf + mb + 48));
      int p = pbase + pxl;
      float* op = out + (size_t)n*(64*HW) + p;
      #pragma unroll
      for (int jj = 0; jj < 4; ++jj) {
        int oc = ks*4 + jj;
        op[(oc     )*HW] = acc0[jj] + bd[oc];
        op[(oc + 16)*HW] = acc1[jj] + bd[oc + 16];
        op[(oc + 32)*HW] = acc2[jj] + bd[oc + 32];
        op[(oc + 48)*HW] = acc3[jj] + bd[oc + 48];
      }
    }
  }
}

// ---------------- launcher ----------------
extern "C" void kernel_launch(void* const* d_in, const int* in_sizes, int n_in,
                              void* d_out, int out_size, void* d_ws, size_t ws_size,
                              hipStream_t stream)
{
  const float* x   = (const float*)d_in[0];
  const float* Wi  = (const float*)d_in[2];
  const float* bi  = (const float*)d_in[3];
  const float* ai  = (const float*)d_in[4];
  const float* Wo  = (const float*)d_in[5];
  const float* bo  = (const float*)d_in[6];
  const float* aof = (const float*)d_in[7];
  const float* Wom = (const float*)d_in[8];
  const float* bom = (const float*)d_in[9];
  const float* Wd  = (const float*)d_in[10];
  const float* bd  = (const float*)d_in[11];
  float* out = (float*)d_out;

  __half* feat = (__half*)d_ws;
  __half* offf = feat + (size_t)NIMG*HW*64;
  __half* Waf  = offf + (size_t)NIMG*HW*64;
  __half* Womf = Waf + 36864;
  __half* Wff  = Womf + 18432;
  __half* Wof  = Wff + 2048;

  hipLaunchKernelGGL(k_wprep, dim3(240),         dim3(256), 0, stream,
                     Wd, Wom, Wi, Wo, Waf, Womf, Wff, Wof);
  hipLaunchKernelGGL(k_front, dim3(NIMG*HW/32),  dim3(256), 0, stream,
                     x, Wff, Wof, bi, ai, bo, aof, feat, offf);
  hipLaunchKernelGGL(k_dcn,   dim3(1024),        dim3(256), 0, stream,
                     feat, offf, Waf, Womf, bom, bd, out);
}

// Round 18
// 96.414 us; speedup vs baseline: 2.9805x; 2.9805x over previous
//
#include <hip/hip_runtime.h>
#include <hip/hip_fp16.h>
#include <stdint.h>

typedef __attribute__((ext_vector_type(8))) _Float16 f16x8;
typedef __attribute__((ext_vector_type(4))) float f32x4;

#define NIMG 40      // B*T
#define TFR  5
#define CIN  3
#define HH   64
#define WW   64
#define HW   4096
#define PPS  72      // LDS row stride for 64-wide front patch
#define RSTR 72      // om region col stride (halves)
#define CSTR 144     // feat window col stride in BYTES (128 data + 16 pad)

union U32H2 { uint u; __half2 h; };

__device__ __forceinline__ ushort4 f4_to_h4(f32x4 a) {
  ushort4 r;
  r.x = __half_as_ushort(__float2half(a[0]));
  r.y = __half_as_ushort(__float2half(a[1]));
  r.z = __half_as_ushort(__float2half(a[2]));
  r.w = __half_as_ushort(__float2half(a[3]));
  return r;
}
__device__ __forceinline__ void h4_add(f32x4& a, ushort4 s) {
  a[0] += __half2float(__ushort_as_half(s.x));
  a[1] += __half2float(__ushort_as_half(s.y));
  a[2] += __half2float(__ushort_as_half(s.z));
  a[3] += __half2float(__ushort_as_half(s.w));
}

// ---------------- K0: weight prep into MFMA-fragment order ----------------
__global__ __launch_bounds__(256) void k_wprep(
    const float* __restrict__ Wd, const float* __restrict__ Wom,
    const float* __restrict__ Wi, const float* __restrict__ Wo,
    __half* __restrict__ Waf, __half* __restrict__ Womf,
    __half* __restrict__ Wff, __half* __restrict__ Wof)
{
  int idx = blockIdx.x*256 + threadIdx.x;
  if (idx < 36864) {                         // Waf [kg2][tap9][ot4][lane][8]
    int j = idx & 7, lane = (idx >> 3) & 63;
    int grp = idx >> 9;                      // 0..71
    int ot = grp & 3, tg = grp >> 2;         // tg 0..17
    int tap = tg % 9, kg = tg / 9;
    int row = lane & 15, ks = lane >> 4;
    int oc = ot*16 + row;
    int c  = kg*32 + ks*8 + j;
    Waf[idx] = __float2half(Wd[oc*576 + c*9 + tap]);
  } else if (idx < 36864 + 18432) {          // Womf [mt2][k0 18][lane][8]
    int q = idx - 36864;
    int j = q & 7, lane = (q >> 3) & 63;
    int grp = q >> 9;                        // 0..35
    int k0 = grp % 18, mt = grp / 18;
    int row = lane & 15, ks = lane >> 4;
    int oc = mt*16 + row;
    int tap = k0 >> 1;
    int c = (k0 & 1)*32 + ks*8 + j;
    Womf[q] = (oc < 27) ? __float2half(Wom[oc*576 + c*9 + tap]) : __float2half(0.f);
  } else if (idx < 36864 + 18432 + 2048) {   // Wff [wv4][lane][8]
    int q = idx - 36864 - 18432;
    int j = q & 7, lane = (q >> 3) & 63;
    int wv = q >> 9;
    int row = lane & 15, ks = lane >> 4;
    int f = wv*16 + row;
    int kk = ks*8 + j;
    Wff[q] = (kk < 27) ? __float2half(Wi[f*27 + kk]) : __float2half(0.f);
  } else if (idx < 36864 + 18432 + 2048 + 4096) {  // Wof [wv4][half2][lane][8]
    int q = idx - 36864 - 18432 - 2048;
    int j = q & 7, lane = (q >> 3) & 63;
    int grp = q >> 9;                        // 0..7
    int wv = grp >> 1, half = grp & 1;
    int row = lane & 15, ks = lane >> 4;
    int f = wv*16 + row;
    int kk = half*32 + ks*8 + j;
    float v = 0.f;
    if (kk < 27)       v = Wo[f*54 + 27 + kk];
    else if (kk < 54)  v = Wo[f*54 + (kk - 27)];
    Wof[q] = __float2half(v);
  }
}

// ---------------- K1: fused feat + off_feat via MFMA [NHWC fp16 out] ----------------
__global__ __launch_bounds__(256) void k_front(
    const float* __restrict__ x,
    const __half* __restrict__ Wff, const __half* __restrict__ Wof,
    const float* __restrict__ bi, const float* __restrict__ ai,
    const float* __restrict__ bo, const float* __restrict__ aof,
    __half* __restrict__ feat, __half* __restrict__ offf)
{
  __shared__ __align__(16) __half sp[32*PPS];
  int t = threadIdx.x, blk = blockIdx.x;
  int n = blk >> 7;
  int pbase = (blk & 127) * 32;
  int h = pbase >> 6;
  int wbase = pbase & 63;
  int n0 = (n/TFR)*TFR;
  const float* xc = x + (size_t)n*(CIN*HW);
  const float* xr = x + (size_t)n0*(CIN*HW);

  #pragma unroll
  for (int i = 0; i < 8; ++i) {
    int e = i*256 + t;
    int kk = e >> 5, px = e & 31;
    float v = 0.f;
    if (kk < 54) {
      int cur = (kk < 27);
      int kb = cur ? kk : kk - 27;
      int c = kb / 9, k = kb - c*9;
      int y  = h + k/3 - 1;
      int xx = wbase + px + (k - (k/3)*3) - 1;
      if (y >= 0 && y < HH && xx >= 0 && xx < WW)
        v = (cur ? xc : xr)[c*HW + y*WW + xx];
    }
    sp[px*PPS + kk] = __float2half(v);
  }
  __syncthreads();

  int wv = t >> 6, lane = t & 63;
  int row = lane & 15, ks = lane >> 4;
  f16x8 af0 = *(const f16x8*)(Wff + (wv<<9) + lane*8);
  f16x8 aw0 = *(const f16x8*)(Wof + (wv<<10) + lane*8);
  f16x8 aw1 = *(const f16x8*)(Wof + (wv<<10) + 512 + lane*8);
  #pragma unroll
  for (int nt = 0; nt < 2; ++nt) {
    const __half* bp = sp + (nt*16 + row)*PPS + ks*8;
    f16x8 b0 = *(const f16x8*)(bp);
    f16x8 b1 = *(const f16x8*)(bp + 32);
    f32x4 accf = {0.f,0.f,0.f,0.f}, acco = {0.f,0.f,0.f,0.f};
    accf = __builtin_amdgcn_mfma_f32_16x16x32_f16(af0, b0, accf, 0, 0, 0);
    acco = __builtin_amdgcn_mfma_f32_16x16x32_f16(aw0, b0, acco, 0, 0, 0);
    acco = __builtin_amdgcn_mfma_f32_16x16x32_f16(aw1, b1, acco, 0, 0, 0);
    int p  = pbase + nt*16 + row;
    int f0 = wv*16 + ks*4;
    size_t base = ((size_t)n*HW + p)*64 + f0;
    union { ushort4 u; __half b[4]; } pf, po;
    #pragma unroll
    for (int j = 0; j < 4; ++j) {
      float vf = accf[j] + bi[f0+j];
      float aF = ai[f0+j];
      vf = vf >= 0.f ? vf : aF*vf;
      pf.b[j] = __float2half(vf);
      float vo = acco[j] + bo[f0+j];
      float aO = aof[f0+j];
      vo = vo >= 0.f ? vo : aO*vo;
      po.b[j] = __float2half(vo);
    }
    *(ushort4*)(feat + base) = pf.u;
    *(ushort4*)(offf + base) = po.u;
  }
}

// ---------------- K2: fused om-head + DCN; 512 threads / 8 waves per 32-px block ----------------
// wave wv: nt=wv&1 (px-tile), kg=(wv>>1)&1 (chan-half), oh=wv>>2 (oc-pair).
__global__ __launch_bounds__(512, 8) void k_dcn(
    const __half* __restrict__ feat, const __half* __restrict__ offf,
    const __half* __restrict__ Waf, const __half* __restrict__ Womf,
    const float* __restrict__ bom, const float* __restrict__ bd,
    float* __restrict__ out)
{
  __shared__ __align__(16) char smem[5*36*CSTR];  // 25920B: om region, then feat window
  __shared__ __align__(16) char smem2[6912];      // soff(2304)+swgt(4608); later mbuf f16 [32][72]
  __shared__ __half som[27*36];                   // om values, padded stride 36
  __shared__ int sflag;
  ushort4* soff = (ushort4*)smem2;                // [32*9] window-relative byte offsets (u16)
  uint4*   swgt = (uint4*)(smem2 + 2304);         // [32*9] corner weights pre-broadcast half2
  __half*  mbuf = (__half*)smem2;                 // [32 px][72] f16 partials (after P4)

  int t = threadIdx.x;
  int blk = blockIdx.x;
  int work = (blk & 7)*640 + (blk >> 3);          // XCD-contiguous: 5 images per XCD
  int n = work >> 7;
  int pbase = (work & 127) * 32;
  int hrow = pbase >> 6, wbase = pbase & 63;
  int wv = t >> 6, lane = t & 63;
  int row = lane & 15, ks = lane >> 4;
  int nt = wv & 1, kg = (wv >> 1) & 1, oh = wv >> 2;
  int pxl = nt*16 + row;
  int cb = kg*64 + ks*16;

  const char* ob = (const char*)(offf + (size_t)n*(HW*64));
  const char* fb = (const char*)(feat + (size_t)n*(HW*64));
  __half* region = (__half*)smem;
  char* sfeat = smem;

  if (t == 0) sflag = 1;

  // ---- P0a: issue feat-window loads into registers (held across P1) ----
  uint4 wreg0 = make_uint4(0,0,0,0), wreg1 = wreg0, wreg2 = wreg0;
  {
    int u0 = t, u1 = 512 + t, u2 = 1024 + t;
    {
      int r = u0 / 288, rem = u0 - r*288, ci = rem >> 3, q = rem & 7;
      int y = hrow - 2 + r, xx = wbase - 2 + ci;
      if ((unsigned)y < 64u && (unsigned)xx < 64u)
        wreg0 = *(const uint4*)(fb + (((y<<6)+xx)<<7) + q*16);
    }
    {
      int r = u1 / 288, rem = u1 - r*288, ci = rem >> 3, q = rem & 7;
      int y = hrow - 2 + r, xx = wbase - 2 + ci;
      if ((unsigned)y < 64u && (unsigned)xx < 64u)
        wreg1 = *(const uint4*)(fb + (((y<<6)+xx)<<7) + q*16);
    }
    if (u2 < 1440) {
      int r = u2 / 288, rem = u2 - r*288, ci = rem >> 3, q = rem & 7;
      int y = hrow - 2 + r, xx = wbase - 2 + ci;
      if ((unsigned)y < 64u && (unsigned)xx < 64u)
        wreg2 = *(const uint4*)(fb + (((y<<6)+xx)<<7) + q*16);
    }
  }

  // ---- P0b: stage off_feat region rows hrow-1..+1, cols wbase-1..+32 ----
  for (int u = t; u < 816; u += 512) {            // 3*34*8 uint4 units
    int ry = u / 272;
    int rem = u - ry*272;
    int rx = rem >> 3, q = rem & 7;
    int y = hrow + ry - 1, xx = wbase + rx - 1;
    uint4 v = make_uint4(0,0,0,0);
    if ((unsigned)y < 64u && (unsigned)xx < 64u)
      v = *(const uint4*)(ob + (((y<<6)+xx)<<7) + q*16);
    *(uint4*)((char*)region + ((ry*34 + rx)*RSTR + q*8)*2) = v;
  }
  __syncthreads();

  // ---- P1: om head (kg==0 waves: mt=oh, ntp=nt) ----
  if (kg == 0) {
    int mt = oh;
    f32x4 acc = {0.f,0.f,0.f,0.f};
    #pragma unroll
    for (int k0 = 0; k0 < 18; ++k0) {
      int k = k0 >> 1, ky = k/3, kx = k - ky*3;
      int c0 = (k0 & 1)*32;
      f16x8 a = *(const f16x8*)(Womf + ((mt*18 + k0)<<9) + lane*8);
      f16x8 b = *(const f16x8*)(region + (ky*34 + pxl + kx)*RSTR + c0 + ks*8);
      acc = __builtin_amdgcn_mfma_f32_16x16x32_f16(a, b, acc, 0, 0, 0);
    }
    #pragma unroll
    for (int j = 0; j < 4; ++j) {
      int oc = mt*16 + ks*4 + j;
      if (oc < 27) {
        float r = acc[j] + bom[oc];
        if (oc >= 18) r = 1.f/(1.f + __expf(-r));
        som[oc*36 + pxl] = __float2half(r);
      }
    }
  }
  __syncthreads();                                // region reads done; som visible

  // ---- P2a: write held window regs -> LDS (overwrites region) ----
  {
    int u0 = t, u1 = 512 + t, u2 = 1024 + t;
    {
      int r = u0 / 288, rem = u0 - r*288, ci = rem >> 3, q = rem & 7;
      *(uint4*)(sfeat + (r*36 + ci)*CSTR + q*16) = wreg0;
    }
    {
      int r = u1 / 288, rem = u1 - r*288, ci = rem >> 3, q = rem & 7;
      *(uint4*)(sfeat + (r*36 + ci)*CSTR + q*16) = wreg1;
    }
    if (u2 < 1440) {
      int r = u2 / 288, rem = u2 - r*288, ci = rem >> 3, q = rem & 7;
      *(uint4*)(sfeat + (r*36 + ci)*CSTR + q*16) = wreg2;
    }
  }

  // ---- P2b: params -> soff/swgt (window-relative) + block flag ----
  if (t < 288) {
    int e = t;
    int px = e / 9, k = e - px*9;
    int w = wbase + px;
    float dy = __half2float(som[(2*k)*36 + px]);
    float dx = __half2float(som[(2*k+1)*36 + px]);
    float m  = __half2float(som[(18+k)*36 + px]);
    float py = (float)(hrow + (k/3) - 1) + dy;
    float qx = (float)(w + (k - (k/3)*3) - 1) + dx;
    float y0f = floorf(py), x0f = floorf(qx);
    float wy = py - y0f, wx = qx - x0f;
    int y0 = (int)y0f, x0 = (int)x0f;
    int y1 = y0 + 1, x1 = x0 + 1;
    float w00 = (1.f-wy)*(1.f-wx)*m;
    float w01 = (1.f-wy)*wx*m;
    float w10 = wy*(1.f-wx)*m;
    float w11 = wy*wx*m;
    if (y0 < 0 || y0 >= HH) { w00 = 0.f; w01 = 0.f; }
    if (y1 < 0 || y1 >= HH) { w10 = 0.f; w11 = 0.f; }
    if (x0 < 0 || x0 >= WW) { w00 = 0.f; w10 = 0.f; }
    if (x1 < 0 || x1 >= WW) { w01 = 0.f; w11 = 0.f; }
    int y0c = min(max(y0,0),HH-1), y1c = min(max(y1,0),HH-1);
    int x0c = min(max(x0,0),WW-1), x1c = min(max(x1,0),WW-1);
    int yw0 = y0c - (hrow-2), yw1 = y1c - (hrow-2);
    int xw0 = x0c - (wbase-2), xw1 = x1c - (wbase-2);
    bool ok = ((unsigned)yw0 < 5u) & ((unsigned)yw1 < 5u)
            & ((unsigned)xw0 < 36u) & ((unsigned)xw1 < 36u);
    if (!ok) atomicAnd(&sflag, 0);
    int cy0 = min(max(yw0,0),4), cy1 = min(max(yw1,0),4);
    int cx0 = min(max(xw0,0),35), cx1 = min(max(xw1,0),35);
    soff[e] = make_ushort4((ushort)((cy0*36 + cx0)*CSTR), (ushort)((cy0*36 + cx1)*CSTR),
                           (ushort)((cy1*36 + cx0)*CSTR), (ushort)((cy1*36 + cx1)*CSTR));
    U32H2 u00, u01, u10, u11;
    u00.h = __float2half2_rn(w00); u01.h = __float2half2_rn(w01);
    u10.h = __float2half2_rn(w10); u11.h = __float2half2_rn(w11);
    swgt[e] = make_uint4(u00.u, u01.u, u10.u, u11.u);
  }
  __syncthreads();

  // ---- P4: 9 taps, (kg chan-half, oh oc-pair) gather -> MFMA ----
  f32x4 acc0 = {0.f,0.f,0.f,0.f}, acc1 = {0.f,0.f,0.f,0.f};
  const __half* afrag = Waf + (kg*9)*2048 + (oh*2)*512 + lane*8;

  if (sflag) {
    // fast path: branch-free LDS gather, fully unrolled
    #pragma unroll
    for (int tap = 0; tap < 9; ++tap) {
      int e = pxl*9 + tap;
      ushort4 off = soff[e];
      uint4 wq  = swgt[e];
      U32H2 W00, W01, W10, W11;
      W00.u = wq.x; W01.u = wq.y; W10.u = wq.z; W11.u = wq.w;
      uint4 c00 = *(const uint4*)(sfeat + (int)off.x + cb);
      uint4 c01 = *(const uint4*)(sfeat + (int)off.y + cb);
      uint4 c10 = *(const uint4*)(sfeat + (int)off.z + cb);
      uint4 c11 = *(const uint4*)(sfeat + (int)off.w + cb);
      uint4 r;
#define BILIN(comp) { U32H2 a0v,a1v,a2v,a3v,res;                                \
      a0v.u = c00.comp; a1v.u = c01.comp; a2v.u = c10.comp; a3v.u = c11.comp;   \
      __half2 v = __hmul2(W00.h, a0v.h); v = __hfma2(W01.h, a1v.h, v);          \
      v = __hfma2(W10.h, a2v.h, v);      v = __hfma2(W11.h, a3v.h, v);          \
      res.h = v; r.comp = res.u; }
      BILIN(x) BILIN(y) BILIN(z) BILIN(w)
      f16x8 b = *(f16x8*)&r;
      const __half* ap = afrag + tap*2048;
      f16x8 a0 = *(const f16x8*)(ap);
      f16x8 a1 = *(const f16x8*)(ap + 512);
      acc0 = __builtin_amdgcn_mfma_f32_16x16x32_f16(a0, b, acc0, 0, 0, 0);
      acc1 = __builtin_amdgcn_mfma_f32_16x16x32_f16(a1, b, acc1, 0, 0, 0);
    }
  } else {
    // slow path (rare): per-lane recompute, clamped global gather, branch-free
    #pragma unroll 1
    for (int tap = 0; tap < 9; ++tap) {
      float dy = __half2float(som[(2*tap)*36 + pxl]);
      float dx = __half2float(som[(2*tap+1)*36 + pxl]);
      float m  = __half2float(som[(18+tap)*36 + pxl]);
      int ky = tap/3, kx = tap - ky*3;
      float py = (float)(hrow + ky - 1) + dy;
      float qx = (float)(wbase + pxl + kx - 1) + dx;
      float y0f = floorf(py), x0f = floorf(qx);
      float wy = py - y0f, wx = qx - x0f;
      int y0 = (int)y0f, x0 = (int)x0f;
      int y1 = y0 + 1, x1 = x0 + 1;
      float w00 = (1.f-wy)*(1.f-wx)*m;
      float w01 = (1.f-wy)*wx*m;
      float w10 = wy*(1.f-wx)*m;
      float w11 = wy*wx*m;
      if (y0 < 0 || y0 >= HH) { w00 = 0.f; w01 = 0.f; }
      if (y1 < 0 || y1 >= HH) { w10 = 0.f; w11 = 0.f; }
      if (x0 < 0 || x0 >= WW) { w00 = 0.f; w10 = 0.f; }
      if (x1 < 0 || x1 >= WW) { w01 = 0.f; w11 = 0.f; }
      int y0c = min(max(y0,0),HH-1), y1c = min(max(y1,0),HH-1);
      int x0c = min(max(x0,0),WW-1), x1c = min(max(x1,0),WW-1);
      int o00 = (((y0c<<6)+x0c)<<7), o01 = (((y0c<<6)+x1c)<<7);
      int o10 = (((y1c<<6)+x0c)<<7), o11 = (((y1c<<6)+x1c)<<7);
      U32H2 W00, W01, W10, W11;
      W00.h = __float2half2_rn(w00); W01.h = __float2half2_rn(w01);
      W10.h = __float2half2_rn(w10); W11.h = __float2half2_rn(w11);
      uint4 c00 = *(const uint4*)(fb + o00 + cb);
      uint4 c01 = *(const uint4*)(fb + o01 + cb);
      uint4 c10 = *(const uint4*)(fb + o10 + cb);
      uint4 c11 = *(const uint4*)(fb + o11 + cb);
      uint4 r;
      BILIN(x) BILIN(y) BILIN(z) BILIN(w)
#undef BILIN
      f16x8 b = *(f16x8*)&r;
      const __half* ap = afrag + tap*2048;
      f16x8 a0 = *(const f16x8*)(ap);
      f16x8 a1 = *(const f16x8*)(ap + 512);
      acc0 = __builtin_amdgcn_mfma_f32_16x16x32_f16(a0, b, acc0, 0, 0, 0);
      acc1 = __builtin_amdgcn_mfma_f32_16x16x32_f16(a1, b, acc1, 0, 0, 0);
    }
  }
  __syncthreads();                                 // soff/swgt dead; mbuf live

  // ---- P5: merge K-halves (f16 partials), epilogue ----
  if (kg == 1) {
    int mb = pxl*72 + oh*32 + ks*4;                // halves; row stride 144B
    *(ushort4*)(mbuf + mb)      = f4_to_h4(acc0);
    *(ushort4*)(mbuf + mb + 16) = f4_to_h4(acc1);
  }
  __syncthreads();
  if (kg == 0) {
    int mb = pxl*72 + oh*32 + ks*4;
    h4_add(acc0, *(ushort4*)(mbuf + mb));
    h4_add(acc1, *(ushort4*)(mbuf + mb + 16));
    int p = pbase + pxl;
    float* op = out + (size_t)n*(64*HW) + p;
    #pragma unroll
    for (int j = 0; j < 4; ++j) {
      int oc = oh*32 + ks*4 + j;
      op[(oc     )*HW] = acc0[j] + bd[oc];
      op[(oc + 16)*HW] = acc1[j] + bd[oc + 16];
    }
  }
}

// ---------------- launcher ----------------
extern "C" void kernel_launch(void* const* d_in, const int* in_sizes, int n_in,
                              void* d_out, int out_size, void* d_ws, size_t ws_size,
                              hipStream_t stream)
{
  const float* x   = (const float*)d_in[0];
  const float* Wi  = (const float*)d_in[2];
  const float* bi  = (const float*)d_in[3];
  const float* ai  = (const float*)d_in[4];
  const float* Wo  = (const float*)d_in[5];
  const float* bo  = (const float*)d_in[6];
  const float* aof = (const float*)d_in[7];
  const float* Wom = (const float*)d_in[8];
  const float* bom = (const float*)d_in[9];
  const float* Wd  = (const float*)d_in[10];
  const float* bd  = (const float*)d_in[11];
  float* out = (float*)d_out;

  __half* feat = (__half*)d_ws;
  __half* offf = feat + (size_t)NIMG*HW*64;
  __half* Waf  = offf + (size_t)NIMG*HW*64;
  __half* Womf = Waf + 36864;
  __half* Wff  = Womf + 18432;
  __half* Wof  = Wff + 2048;

  hipLaunchKernelGGL(k_wprep, dim3(240),         dim3(256), 0, stream,
                     Wd, Wom, Wi, Wo, Waf, Womf, Wff, Wof);
  hipLaunchKernelGGL(k_front, dim3(NIMG*HW/32),  dim3(256), 0, stream,
                     x, Wff, Wof, bi, ai, bo, aof, feat, offf);
  hipLaunchKernelGGL(k_dcn,   dim3(NIMG*HW/32),  dim3(512), 0, stream,
                     feat, offf, Waf, Womf, bom, bd, out);
}

// Round 19
// 90.915 us; speedup vs baseline: 3.1607x; 1.0605x over previous
//
#include <hip/hip_runtime.h>
#include <hip/hip_fp16.h>
#include <stdint.h>

typedef __attribute__((ext_vector_type(8))) _Float16 f16x8;
typedef __attribute__((ext_vector_type(4))) float f32x4;

#define NIMG 40      // B*T
#define TFR  5
#define CIN  3
#define HH   64
#define WW   64
#define HW   4096
#define PPS  72      // LDS row stride for 64-wide front patch
#define RSTR 72      // om region col stride (halves)
#define CSTR 144     // feat window col stride in BYTES (128 data + 16 pad)
#define SOMS 34      // som row stride (halves)
#define MBS  68      // mbuf row stride (halves); slab = 32*68 halves

union U32H2 { uint u; __half2 h; };

__device__ __forceinline__ ushort4 f4_to_h4(f32x4 a) {
  ushort4 r;
  r.x = __half_as_ushort(__float2half(a[0]));
  r.y = __half_as_ushort(__float2half(a[1]));
  r.z = __half_as_ushort(__float2half(a[2]));
  r.w = __half_as_ushort(__float2half(a[3]));
  return r;
}
__device__ __forceinline__ void h4_add(f32x4& a, ushort4 s) {
  a[0] += __half2float(__ushort_as_half(s.x));
  a[1] += __half2float(__ushort_as_half(s.y));
  a[2] += __half2float(__ushort_as_half(s.z));
  a[3] += __half2float(__ushort_as_half(s.w));
}

__device__ __forceinline__ uint4 bilin4(uint4 c00, uint4 c01, uint4 c10, uint4 c11, uint4 wq) {
  U32H2 W00, W01, W10, W11;
  W00.u = wq.x; W01.u = wq.y; W10.u = wq.z; W11.u = wq.w;
  uint4 r;
#define BILIN(comp) { U32H2 a0v,a1v,a2v,a3v,res;                                \
  a0v.u = c00.comp; a1v.u = c01.comp; a2v.u = c10.comp; a3v.u = c11.comp;       \
  __half2 v = __hmul2(W00.h, a0v.h); v = __hfma2(W01.h, a1v.h, v);              \
  v = __hfma2(W10.h, a2v.h, v);      v = __hfma2(W11.h, a3v.h, v);              \
  res.h = v; r.comp = res.u; }
  BILIN(x) BILIN(y) BILIN(z) BILIN(w)
#undef BILIN
  return r;
}

// fast-path tap range: LDS gather -> 4 oc-tile MFMAs
template<int T0, int T1>
__device__ __forceinline__ void dcn_taps_fast(
    const char* sfeat, const ushort4* soff, const uint4* swgt,
    const __half* afrag, int pxl, int cb,
    f32x4& acc0, f32x4& acc1, f32x4& acc2, f32x4& acc3)
{
  #pragma unroll
  for (int tap = T0; tap < T1; ++tap) {
    int e = pxl*9 + tap;
    ushort4 off = soff[e];
    uint4 wq  = swgt[e];
    uint4 c00 = *(const uint4*)(sfeat + (int)off.x + cb);
    uint4 c01 = *(const uint4*)(sfeat + (int)off.y + cb);
    uint4 c10 = *(const uint4*)(sfeat + (int)off.z + cb);
    uint4 c11 = *(const uint4*)(sfeat + (int)off.w + cb);
    uint4 r = bilin4(c00, c01, c10, c11, wq);
    f16x8 b = *(f16x8*)&r;
    const __half* ap = afrag + tap*2048;
    f16x8 a0 = *(const f16x8*)(ap);
    f16x8 a1 = *(const f16x8*)(ap + 512);
    f16x8 a2 = *(const f16x8*)(ap + 1024);
    f16x8 a3 = *(const f16x8*)(ap + 1536);
    acc0 = __builtin_amdgcn_mfma_f32_16x16x32_f16(a0, b, acc0, 0, 0, 0);
    acc1 = __builtin_amdgcn_mfma_f32_16x16x32_f16(a1, b, acc1, 0, 0, 0);
    acc2 = __builtin_amdgcn_mfma_f32_16x16x32_f16(a2, b, acc2, 0, 0, 0);
    acc3 = __builtin_amdgcn_mfma_f32_16x16x32_f16(a3, b, acc3, 0, 0, 0);
  }
}

// slow-path tap range: per-lane recompute, clamped global gather
template<int T0, int T1>
__device__ __forceinline__ void dcn_taps_slow(
    const __half* som, const char* fb, const __half* afrag,
    int pxl, int cb, int hrow, int wbase,
    f32x4& acc0, f32x4& acc1, f32x4& acc2, f32x4& acc3)
{
  #pragma unroll 1
  for (int tap = T0; tap < T1; ++tap) {
    float dy = __half2float(som[(2*tap)*SOMS + pxl]);
    float dx = __half2float(som[(2*tap+1)*SOMS + pxl]);
    float m  = __half2float(som[(18+tap)*SOMS + pxl]);
    int ky = tap/3, kx = tap - ky*3;
    float py = (float)(hrow + ky - 1) + dy;
    float qx = (float)(wbase + pxl + kx - 1) + dx;
    float y0f = floorf(py), x0f = floorf(qx);
    float wy = py - y0f, wx = qx - x0f;
    int y0 = (int)y0f, x0 = (int)x0f;
    int y1 = y0 + 1, x1 = x0 + 1;
    float w00 = (1.f-wy)*(1.f-wx)*m;
    float w01 = (1.f-wy)*wx*m;
    float w10 = wy*(1.f-wx)*m;
    float w11 = wy*wx*m;
    if (y0 < 0 || y0 >= HH) { w00 = 0.f; w01 = 0.f; }
    if (y1 < 0 || y1 >= HH) { w10 = 0.f; w11 = 0.f; }
    if (x0 < 0 || x0 >= WW) { w00 = 0.f; w10 = 0.f; }
    if (x1 < 0 || x1 >= WW) { w01 = 0.f; w11 = 0.f; }
    int y0c = min(max(y0,0),HH-1), y1c = min(max(y1,0),HH-1);
    int x0c = min(max(x0,0),WW-1), x1c = min(max(x1,0),WW-1);
    int o00 = (((y0c<<6)+x0c)<<7), o01 = (((y0c<<6)+x1c)<<7);
    int o10 = (((y1c<<6)+x0c)<<7), o11 = (((y1c<<6)+x1c)<<7);
    U32H2 u00, u01, u10, u11;
    u00.h = __float2half2_rn(w00); u01.h = __float2half2_rn(w01);
    u10.h = __float2half2_rn(w10); u11.h = __float2half2_rn(w11);
    uint4 wq = make_uint4(u00.u, u01.u, u10.u, u11.u);
    uint4 c00 = *(const uint4*)(fb + o00 + cb);
    uint4 c01 = *(const uint4*)(fb + o01 + cb);
    uint4 c10 = *(const uint4*)(fb + o10 + cb);
    uint4 c11 = *(const uint4*)(fb + o11 + cb);
    uint4 r = bilin4(c00, c01, c10, c11, wq);
    f16x8 b = *(f16x8*)&r;
    const __half* ap = afrag + tap*2048;
    f16x8 a0 = *(const f16x8*)(ap);
    f16x8 a1 = *(const f16x8*)(ap + 512);
    f16x8 a2 = *(const f16x8*)(ap + 1024);
    f16x8 a3 = *(const f16x8*)(ap + 1536);
    acc0 = __builtin_amdgcn_mfma_f32_16x16x32_f16(a0, b, acc0, 0, 0, 0);
    acc1 = __builtin_amdgcn_mfma_f32_16x16x32_f16(a1, b, acc1, 0, 0, 0);
    acc2 = __builtin_amdgcn_mfma_f32_16x16x32_f16(a2, b, acc2, 0, 0, 0);
    acc3 = __builtin_amdgcn_mfma_f32_16x16x32_f16(a3, b, acc3, 0, 0, 0);
  }
}

// ---------------- K0: weight prep into MFMA-fragment order ----------------
__global__ __launch_bounds__(256) void k_wprep(
    const float* __restrict__ Wd, const float* __restrict__ Wom,
    const float* __restrict__ Wi, const float* __restrict__ Wo,
    __half* __restrict__ Waf, __half* __restrict__ Womf,
    __half* __restrict__ Wff, __half* __restrict__ Wof)
{
  int idx = blockIdx.x*256 + threadIdx.x;
  if (idx < 36864) {                         // Waf [kg2][tap9][ot4][lane][8]
    int j = idx & 7, lane = (idx >> 3) & 63;
    int grp = idx >> 9;                      // 0..71
    int ot = grp & 3, tg = grp >> 2;         // tg 0..17
    int tap = tg % 9, kg = tg / 9;
    int row = lane & 15, ks = lane >> 4;
    int oc = ot*16 + row;
    int c  = kg*32 + ks*8 + j;
    Waf[idx] = __float2half(Wd[oc*576 + c*9 + tap]);
  } else if (idx < 36864 + 18432) {          // Womf [mt2][k0 18][lane][8]
    int q = idx - 36864;
    int j = q & 7, lane = (q >> 3) & 63;
    int grp = q >> 9;                        // 0..35
    int k0 = grp % 18, mt = grp / 18;
    int row = lane & 15, ks = lane >> 4;
    int oc = mt*16 + row;
    int tap = k0 >> 1;
    int c = (k0 & 1)*32 + ks*8 + j;
    Womf[q] = (oc < 27) ? __float2half(Wom[oc*576 + c*9 + tap]) : __float2half(0.f);
  } else if (idx < 36864 + 18432 + 2048) {   // Wff [wv4][lane][8]
    int q = idx - 36864 - 18432;
    int j = q & 7, lane = (q >> 3) & 63;
    int wv = q >> 9;
    int row = lane & 15, ks = lane >> 4;
    int f = wv*16 + row;
    int kk = ks*8 + j;
    Wff[q] = (kk < 27) ? __float2half(Wi[f*27 + kk]) : __float2half(0.f);
  } else if (idx < 36864 + 18432 + 2048 + 4096) {  // Wof [wv4][half2][lane][8]
    int q = idx - 36864 - 18432 - 2048;
    int j = q & 7, lane = (q >> 3) & 63;
    int grp = q >> 9;                        // 0..7
    int wv = grp >> 1, half = grp & 1;
    int row = lane & 15, ks = lane >> 4;
    int f = wv*16 + row;
    int kk = half*32 + ks*8 + j;
    float v = 0.f;
    if (kk < 27)       v = Wo[f*54 + 27 + kk];
    else if (kk < 54)  v = Wo[f*54 + (kk - 27)];
    Wof[q] = __float2half(v);
  }
}

// ---------------- K1: fused feat + off_feat via MFMA [NHWC fp16 out] ----------------
__global__ __launch_bounds__(256) void k_front(
    const float* __restrict__ x,
    const __half* __restrict__ Wff, const __half* __restrict__ Wof,
    const float* __restrict__ bi, const float* __restrict__ ai,
    const float* __restrict__ bo, const float* __restrict__ aof,
    __half* __restrict__ feat, __half* __restrict__ offf)
{
  __shared__ __align__(16) __half sp[32*PPS];
  int t = threadIdx.x, blk = blockIdx.x;
  int n = blk >> 7;
  int pbase = (blk & 127) * 32;
  int h = pbase >> 6;
  int wbase = pbase & 63;
  int n0 = (n/TFR)*TFR;
  const float* xc = x + (size_t)n*(CIN*HW);
  const float* xr = x + (size_t)n0*(CIN*HW);

  #pragma unroll
  for (int i = 0; i < 8; ++i) {
    int e = i*256 + t;
    int kk = e >> 5, px = e & 31;
    float v = 0.f;
    if (kk < 54) {
      int cur = (kk < 27);
      int kb = cur ? kk : kk - 27;
      int c = kb / 9, k = kb - c*9;
      int y  = h + k/3 - 1;
      int xx = wbase + px + (k - (k/3)*3) - 1;
      if (y >= 0 && y < HH && xx >= 0 && xx < WW)
        v = (cur ? xc : xr)[c*HW + y*WW + xx];
    }
    sp[px*PPS + kk] = __float2half(v);
  }
  __syncthreads();

  int wv = t >> 6, lane = t & 63;
  int row = lane & 15, ks = lane >> 4;
  f16x8 af0 = *(const f16x8*)(Wff + (wv<<9) + lane*8);
  f16x8 aw0 = *(const f16x8*)(Wof + (wv<<10) + lane*8);
  f16x8 aw1 = *(const f16x8*)(Wof + (wv<<10) + 512 + lane*8);
  #pragma unroll
  for (int nt = 0; nt < 2; ++nt) {
    const __half* bp = sp + (nt*16 + row)*PPS + ks*8;
    f16x8 b0 = *(const f16x8*)(bp);
    f16x8 b1 = *(const f16x8*)(bp + 32);
    f32x4 accf = {0.f,0.f,0.f,0.f}, acco = {0.f,0.f,0.f,0.f};
    accf = __builtin_amdgcn_mfma_f32_16x16x32_f16(af0, b0, accf, 0, 0, 0);
    acco = __builtin_amdgcn_mfma_f32_16x16x32_f16(aw0, b0, acco, 0, 0, 0);
    acco = __builtin_amdgcn_mfma_f32_16x16x32_f16(aw1, b1, acco, 0, 0, 0);
    int p  = pbase + nt*16 + row;
    int f0 = wv*16 + ks*4;
    size_t base = ((size_t)n*HW + p)*64 + f0;
    union { ushort4 u; __half b[4]; } pf, po;
    #pragma unroll
    for (int j = 0; j < 4; ++j) {
      float vf = accf[j] + bi[f0+j];
      float aF = ai[f0+j];
      vf = vf >= 0.f ? vf : aF*vf;
      pf.b[j] = __float2half(vf);
      float vo = acco[j] + bo[f0+j];
      float aO = aof[f0+j];
      vo = vo >= 0.f ? vo : aO*vo;
      po.b[j] = __float2half(vo);
    }
    *(ushort4*)(feat + base) = pf.u;
    *(ushort4*)(offf + base) = po.u;
  }
}

// ---------------- K2: fused om+DCN; 512 thr, tap-split (no duplication) ----------------
// wave wv: nt=wv&1 (px-tile), kg=(wv>>1)&1 (chan-half), tg=wv>>2 (tap-group 0-4 / 5-8).
__global__ __launch_bounds__(512, 8) void k_dcn(
    const __half* __restrict__ feat, const __half* __restrict__ offf,
    const __half* __restrict__ Waf, const __half* __restrict__ Womf,
    const float* __restrict__ bom, const float* __restrict__ bd,
    float* __restrict__ out)
{
  __shared__ __align__(16) char smem[5*36*CSTR];  // 25920B: om region, then feat window
  __shared__ __align__(16) char smem2[13056];     // soff(2304)+swgt(4608); later 3 mbuf slabs
  __shared__ __half som[27*SOMS];                 // om values (1836B)
  __shared__ int sflag;
  ushort4* soff = (ushort4*)smem2;
  uint4*   swgt = (uint4*)(smem2 + 2304);
  __half*  mbuf = (__half*)smem2;                 // 3 slabs x [32][MBS] f16 (after P4)

  int t = threadIdx.x;
  int blk = blockIdx.x;
  int work = (blk & 7)*640 + (blk >> 3);          // XCD-contiguous: 5 images per XCD
  int n = work >> 7;
  int pbase = (work & 127) * 32;
  int hrow = pbase >> 6, wbase = pbase & 63;
  int wv = t >> 6, lane = t & 63;
  int row = lane & 15, ks = lane >> 4;
  int nt = wv & 1, kg = (wv >> 1) & 1, tg = wv >> 2;
  int pxl = nt*16 + row;
  int cb = kg*64 + ks*16;

  const char* ob = (const char*)(offf + (size_t)n*(HW*64));
  const char* fb = (const char*)(feat + (size_t)n*(HW*64));
  __half* region = (__half*)smem;
  char* sfeat = smem;

  if (t == 0) sflag = 1;

  // ---- P0a: issue feat-window loads into registers (held across P1) ----
  uint4 wreg0 = make_uint4(0,0,0,0), wreg1 = wreg0, wreg2 = wreg0;
  {
    int u0 = t, u1 = 512 + t, u2 = 1024 + t;
    {
      int r = u0 / 288, rem = u0 - r*288, ci = rem >> 3, q = rem & 7;
      int y = hrow - 2 + r, xx = wbase - 2 + ci;
      if ((unsigned)y < 64u && (unsigned)xx < 64u)
        wreg0 = *(const uint4*)(fb + (((y<<6)+xx)<<7) + q*16);
    }
    {
      int r = u1 / 288, rem = u1 - r*288, ci = rem >> 3, q = rem & 7;
      int y = hrow - 2 + r, xx = wbase - 2 + ci;
      if ((unsigned)y < 64u && (unsigned)xx < 64u)
        wreg1 = *(const uint4*)(fb + (((y<<6)+xx)<<7) + q*16);
    }
    if (u2 < 1440) {
      int r = u2 / 288, rem = u2 - r*288, ci = rem >> 3, q = rem & 7;
      int y = hrow - 2 + r, xx = wbase - 2 + ci;
      if ((unsigned)y < 64u && (unsigned)xx < 64u)
        wreg2 = *(const uint4*)(fb + (((y<<6)+xx)<<7) + q*16);
    }
  }

  // ---- P0b: stage off_feat region rows hrow-1..+1, cols wbase-1..+32 ----
  for (int u = t; u < 816; u += 512) {            // 3*34*8 uint4 units
    int ry = u / 272;
    int rem = u - ry*272;
    int rx = rem >> 3, q = rem & 7;
    int y = hrow + ry - 1, xx = wbase + rx - 1;
    uint4 v = make_uint4(0,0,0,0);
    if ((unsigned)y < 64u && (unsigned)xx < 64u)
      v = *(const uint4*)(ob + (((y<<6)+xx)<<7) + q*16);
    *(uint4*)((char*)region + ((ry*34 + rx)*RSTR + q*8)*2) = v;
  }
  __syncthreads();

  // ---- P1: om head on kg==0 waves (mt=tg, nt) ----
  if (kg == 0) {
    int mt = tg;
    f32x4 acc = {0.f,0.f,0.f,0.f};
    #pragma unroll
    for (int k0 = 0; k0 < 18; ++k0) {
      int k = k0 >> 1, ky = k/3, kx = k - ky*3;
      int c0 = (k0 & 1)*32;
      f16x8 a = *(const f16x8*)(Womf + ((mt*18 + k0)<<9) + lane*8);
      f16x8 b = *(const f16x8*)(region + (ky*34 + pxl + kx)*RSTR + c0 + ks*8);
      acc = __builtin_amdgcn_mfma_f32_16x16x32_f16(a, b, acc, 0, 0, 0);
    }
    #pragma unroll
    for (int j = 0; j < 4; ++j) {
      int oc = mt*16 + ks*4 + j;
      if (oc < 27) {
        float r = acc[j] + bom[oc];
        if (oc >= 18) r = 1.f/(1.f + __expf(-r));
        som[oc*SOMS + pxl] = __float2half(r);
      }
    }
  }
  __syncthreads();                                // region reads done; som visible

  // ---- P2a: write held window regs -> LDS (overwrites region) ----
  {
    int u0 = t, u1 = 512 + t, u2 = 1024 + t;
    {
      int r = u0 / 288, rem = u0 - r*288, ci = rem >> 3, q = rem & 7;
      *(uint4*)(sfeat + (r*36 + ci)*CSTR + q*16) = wreg0;
    }
    {
      int r = u1 / 288, rem = u1 - r*288, ci = rem >> 3, q = rem & 7;
      *(uint4*)(sfeat + (r*36 + ci)*CSTR + q*16) = wreg1;
    }
    if (u2 < 1440) {
      int r = u2 / 288, rem = u2 - r*288, ci = rem >> 3, q = rem & 7;
      *(uint4*)(sfeat + (r*36 + ci)*CSTR + q*16) = wreg2;
    }
  }

  // ---- P2b: params -> soff/swgt + block flag ----
  if (t < 288) {
    int e = t;
    int px = e / 9, k = e - px*9;
    int w = wbase + px;
    float dy = __half2float(som[(2*k)*SOMS + px]);
    float dx = __half2float(som[(2*k+1)*SOMS + px]);
    float m  = __half2float(som[(18+k)*SOMS + px]);
    float py = (float)(hrow + (k/3) - 1) + dy;
    float qx = (float)(w + (k - (k/3)*3) - 1) + dx;
    float y0f = floorf(py), x0f = floorf(qx);
    float wy = py - y0f, wx = qx - x0f;
    int y0 = (int)y0f, x0 = (int)x0f;
    int y1 = y0 + 1, x1 = x0 + 1;
    float w00 = (1.f-wy)*(1.f-wx)*m;
    float w01 = (1.f-wy)*wx*m;
    float w10 = wy*(1.f-wx)*m;
    float w11 = wy*wx*m;
    if (y0 < 0 || y0 >= HH) { w00 = 0.f; w01 = 0.f; }
    if (y1 < 0 || y1 >= HH) { w10 = 0.f; w11 = 0.f; }
    if (x0 < 0 || x0 >= WW) { w00 = 0.f; w10 = 0.f; }
    if (x1 < 0 || x1 >= WW) { w01 = 0.f; w11 = 0.f; }
    int y0c = min(max(y0,0),HH-1), y1c = min(max(y1,0),HH-1);
    int x0c = min(max(x0,0),WW-1), x1c = min(max(x1,0),WW-1);
    int yw0 = y0c - (hrow-2), yw1 = y1c - (hrow-2);
    int xw0 = x0c - (wbase-2), xw1 = x1c - (wbase-2);
    bool ok = ((unsigned)yw0 < 5u) & ((unsigned)yw1 < 5u)
            & ((unsigned)xw0 < 36u) & ((unsigned)xw1 < 36u);
    if (!ok) atomicAnd(&sflag, 0);
    int cy0 = min(max(yw0,0),4), cy1 = min(max(yw1,0),4);
    int cx0 = min(max(xw0,0),35), cx1 = min(max(xw1,0),35);
    soff[e] = make_ushort4((ushort)((cy0*36 + cx0)*CSTR), (ushort)((cy0*36 + cx1)*CSTR),
                           (ushort)((cy1*36 + cx0)*CSTR), (ushort)((cy1*36 + cx1)*CSTR));
    U32H2 u00, u01, u10, u11;
    u00.h = __float2half2_rn(w00); u01.h = __float2half2_rn(w01);
    u10.h = __float2half2_rn(w10); u11.h = __float2half2_rn(w11);
    swgt[e] = make_uint4(u00.u, u01.u, u10.u, u11.u);
  }
  __syncthreads();

  // ---- P4: tap-group gather -> 4 oc-tile MFMAs ----
  f32x4 acc0 = {0.f,0.f,0.f,0.f}, acc1 = {0.f,0.f,0.f,0.f};
  f32x4 acc2 = {0.f,0.f,0.f,0.f}, acc3 = {0.f,0.f,0.f,0.f};
  const __half* afrag = Waf + (kg*9)*2048 + lane*8;
  if (sflag) {
    if (tg == 0) dcn_taps_fast<0,5>(sfeat, soff, swgt, afrag, pxl, cb, acc0, acc1, acc2, acc3);
    else         dcn_taps_fast<5,9>(sfeat, soff, swgt, afrag, pxl, cb, acc0, acc1, acc2, acc3);
  } else {
    if (tg == 0) dcn_taps_slow<0,5>(som, fb, afrag, pxl, cb, hrow, wbase, acc0, acc1, acc2, acc3);
    else         dcn_taps_slow<5,9>(som, fb, afrag, pxl, cb, hrow, wbase, acc0, acc1, acc2, acc3);
  }
  __syncthreads();                                // soff/swgt dead; mbuf live

  // ---- P5: merge 4 partials per px-tile (3 writer slabs + reader) ----
  int slab = kg*2 + tg - 1;                       // writers: (kg,tg) != (0,0)
  if (wv >= 2 || tg == 1) {                       // i.e. not (kg==0 && tg==0)
    int mb = slab*(32*MBS) + pxl*MBS + ks*4;
    *(ushort4*)(mbuf + mb)      = f4_to_h4(acc0);
    *(ushort4*)(mbuf + mb + 16) = f4_to_h4(acc1);
    *(ushort4*)(mbuf + mb + 32) = f4_to_h4(acc2);
    *(ushort4*)(mbuf + mb + 48) = f4_to_h4(acc3);
  }
  __syncthreads();
  if (kg == 0 && tg == 0) {
    int mb = pxl*MBS + ks*4;
    #pragma unroll
    for (int s = 0; s < 3; ++s) {
      h4_add(acc0, *(ushort4*)(mbuf + s*(32*MBS) + mb));
      h4_add(acc1, *(ushort4*)(mbuf + s*(32*MBS) + mb + 16));
      h4_add(acc2, *(ushort4*)(mbuf + s*(32*MBS) + mb + 32));
      h4_add(acc3, *(ushort4*)(mbuf + s*(32*MBS) + mb + 48));
    }
    int p = pbase + pxl;
    float* op = out + (size_t)n*(64*HW) + p;
    #pragma unroll
    for (int j = 0; j < 4; ++j) {
      int oc = ks*4 + j;
      op[(oc     )*HW] = acc0[j] + bd[oc];
      op[(oc + 16)*HW] = acc1[j] + bd[oc + 16];
      op[(oc + 32)*HW] = acc2[j] + bd[oc + 32];
      op[(oc + 48)*HW] = acc3[j] + bd[oc + 48];
    }
  }
}

// ---------------- launcher ----------------
extern "C" void kernel_launch(void* const* d_in, const int* in_sizes, int n_in,
                              void* d_out, int out_size, void* d_ws, size_t ws_size,
                              hipStream_t stream)
{
  const float* x   = (const float*)d_in[0];
  const float* Wi  = (const float*)d_in[2];
  const float* bi  = (const float*)d_in[3];
  const float* ai  = (const float*)d_in[4];
  const float* Wo  = (const float*)d_in[5];
  const float* bo  = (const float*)d_in[6];
  const float* aof = (const float*)d_in[7];
  const float* Wom = (const float*)d_in[8];
  const float* bom = (const float*)d_in[9];
  const float* Wd  = (const float*)d_in[10];
  const float* bd  = (const float*)d_in[11];
  float* out = (float*)d_out;

  __half* feat = (__half*)d_ws;
  __half* offf = feat + (size_t)NIMG*HW*64;
  __half* Waf  = offf + (size_t)NIMG*HW*64;
  __half* Womf = Waf + 36864;
  __half* Wff  = Womf + 18432;
  __half* Wof  = Wff + 2048;

  hipLaunchKernelGGL(k_wprep, dim3(240),         dim3(256), 0, stream,
                     Wd, Wom, Wi, Wo, Waf, Womf, Wff, Wof);
  hipLaunchKernelGGL(k_front, dim3(NIMG*HW/32),  dim3(256), 0, stream,
                     x, Wff, Wof, bi, ai, bo, aof, feat, offf);
  hipLaunchKernelGGL(k_dcn,   dim3(NIMG*HW/32),  dim3(512), 0, stream,
                     feat, offf, Waf, Womf, bom, bd, out);
}

// Round 20
// 87.012 us; speedup vs baseline: 3.3025x; 1.0449x over previous
//
#include <hip/hip_runtime.h>
#include <hip/hip_fp16.h>
#include <stdint.h>

typedef __attribute__((ext_vector_type(8))) _Float16 f16x8;
typedef __attribute__((ext_vector_type(4))) float f32x4;

#define NIMG 40      // B*T
#define TFR  5
#define CIN  3
#define HH   64
#define WW   64
#define HW   4096
#define PPS  72      // LDS row stride for 64-wide front patch
#define RSTR 72      // om region col stride (halves)
#define CSTR 144     // feat window col stride in BYTES (128 data + 16 pad)

union U32H2 { uint u; __half2 h; };

__device__ __forceinline__ ushort4 f4_to_h4(f32x4 a) {
  ushort4 r;
  r.x = __half_as_ushort(__float2half(a[0]));
  r.y = __half_as_ushort(__float2half(a[1]));
  r.z = __half_as_ushort(__float2half(a[2]));
  r.w = __half_as_ushort(__float2half(a[3]));
  return r;
}
__device__ __forceinline__ void h4_add(f32x4& a, ushort4 s) {
  a[0] += __half2float(__ushort_as_half(s.x));
  a[1] += __half2float(__ushort_as_half(s.y));
  a[2] += __half2float(__ushort_as_half(s.z));
  a[3] += __half2float(__ushort_as_half(s.w));
}

// ---------------- K0: weight prep into MFMA-fragment order ----------------
// All layouts: [frag][lane=64][8 halves] -> wave A-load = uniform base + lane*16B.
__global__ __launch_bounds__(256) void k_wprep(
    const float* __restrict__ Wd, const float* __restrict__ Wom,
    const float* __restrict__ Wi, const float* __restrict__ Wo,
    __half* __restrict__ Waf, __half* __restrict__ Womf,
    __half* __restrict__ Wff, __half* __restrict__ Wof)
{
  int idx = blockIdx.x*256 + threadIdx.x;
  if (idx < 36864) {                         // Waf [kg2][tap9][ot4][lane][8]
    int j = idx & 7, lane = (idx >> 3) & 63;
    int grp = idx >> 9;                      // 0..71
    int ot = grp & 3, tg = grp >> 2;         // tg 0..17
    int tap = tg % 9, kg = tg / 9;
    int row = lane & 15, ks = lane >> 4;
    int oc = ot*16 + row;
    int c  = kg*32 + ks*8 + j;
    Waf[idx] = __float2half(Wd[oc*576 + c*9 + tap]);
  } else if (idx < 36864 + 18432) {          // Womf [mt2][k0 18][lane][8]
    int q = idx - 36864;
    int j = q & 7, lane = (q >> 3) & 63;
    int grp = q >> 9;                        // 0..35
    int k0 = grp % 18, mt = grp / 18;
    int row = lane & 15, ks = lane >> 4;
    int oc = mt*16 + row;
    int tap = k0 >> 1;
    int c = (k0 & 1)*32 + ks*8 + j;
    Womf[q] = (oc < 27) ? __float2half(Wom[oc*576 + c*9 + tap]) : __float2half(0.f);
  } else if (idx < 36864 + 18432 + 2048) {   // Wff [wv4][lane][8]
    int q = idx - 36864 - 18432;
    int j = q & 7, lane = (q >> 3) & 63;
    int wv = q >> 9;
    int row = lane & 15, ks = lane >> 4;
    int f = wv*16 + row;
    int kk = ks*8 + j;
    Wff[q] = (kk < 27) ? __float2half(Wi[f*27 + kk]) : __float2half(0.f);
  } else if (idx < 36864 + 18432 + 2048 + 4096) {  // Wof [wv4][half2][lane][8]
    int q = idx - 36864 - 18432 - 2048;
    int j = q & 7, lane = (q >> 3) & 63;
    int grp = q >> 9;                        // 0..7
    int wv = grp >> 1, half = grp & 1;
    int row = lane & 15, ks = lane >> 4;
    int f = wv*16 + row;
    int kk = half*32 + ks*8 + j;
    float v = 0.f;
    if (kk < 27)       v = Wo[f*54 + 27 + kk];
    else if (kk < 54)  v = Wo[f*54 + (kk - 27)];
    Wof[q] = __float2half(v);
  }
}

// ---------------- K1: fused feat + off_feat via MFMA [NHWC fp16 out] ----------------
__global__ __launch_bounds__(256) void k_front(
    const float* __restrict__ x,
    const __half* __restrict__ Wff, const __half* __restrict__ Wof,
    const float* __restrict__ bi, const float* __restrict__ ai,
    const float* __restrict__ bo, const float* __restrict__ aof,
    __half* __restrict__ feat, __half* __restrict__ offf)
{
  __shared__ __align__(16) __half sp[32*PPS];
  int t = threadIdx.x, blk = blockIdx.x;
  int n = blk >> 7;
  int pbase = (blk & 127) * 32;
  int h = pbase >> 6;
  int wbase = pbase & 63;
  int n0 = (n/TFR)*TFR;
  const float* xc = x + (size_t)n*(CIN*HW);
  const float* xr = x + (size_t)n0*(CIN*HW);

  #pragma unroll
  for (int i = 0; i < 8; ++i) {
    int e = i*256 + t;
    int kk = e >> 5, px = e & 31;
    float v = 0.f;
    if (kk < 54) {
      int cur = (kk < 27);
      int kb = cur ? kk : kk - 27;
      int c = kb / 9, k = kb - c*9;
      int y  = h + k/3 - 1;
      int xx = wbase + px + (k - (k/3)*3) - 1;
      if (y >= 0 && y < HH && xx >= 0 && xx < WW)
        v = (cur ? xc : xr)[c*HW + y*WW + xx];
    }
    sp[px*PPS + kk] = __float2half(v);
  }
  __syncthreads();

  int wv = t >> 6, lane = t & 63;
  int row = lane & 15, ks = lane >> 4;
  f16x8 af0 = *(const f16x8*)(Wff + (wv<<9) + lane*8);
  f16x8 aw0 = *(const f16x8*)(Wof + (wv<<10) + lane*8);
  f16x8 aw1 = *(const f16x8*)(Wof + (wv<<10) + 512 + lane*8);
  #pragma unroll
  for (int nt = 0; nt < 2; ++nt) {
    const __half* bp = sp + (nt*16 + row)*PPS + ks*8;
    f16x8 b0 = *(const f16x8*)(bp);
    f16x8 b1 = *(const f16x8*)(bp + 32);
    f32x4 accf = {0.f,0.f,0.f,0.f}, acco = {0.f,0.f,0.f,0.f};
    accf = __builtin_amdgcn_mfma_f32_16x16x32_f16(af0, b0, accf, 0, 0, 0);
    acco = __builtin_amdgcn_mfma_f32_16x16x32_f16(aw0, b0, acco, 0, 0, 0);
    acco = __builtin_amdgcn_mfma_f32_16x16x32_f16(aw1, b1, acco, 0, 0, 0);
    int p  = pbase + nt*16 + row;
    int f0 = wv*16 + ks*4;
    size_t base = ((size_t)n*HW + p)*64 + f0;
    union { ushort4 u; __half b[4]; } pf, po;
    #pragma unroll
    for (int j = 0; j < 4; ++j) {
      float vf = accf[j] + bi[f0+j];
      float aF = ai[f0+j];
      vf = vf >= 0.f ? vf : aF*vf;
      pf.b[j] = __float2half(vf);
      float vo = acco[j] + bo[f0+j];
      float aO = aof[f0+j];
      vo = vo >= 0.f ? vo : aO*vo;
      po.b[j] = __float2half(vo);
    }
    *(ushort4*)(feat + base) = pf.u;
    *(ushort4*)(offf + base) = po.u;
  }
}

// ---------------- K2: fused om-head + DCN, T14 async window stage ----------------
// P0: issue region+window loads (window held in 24 VGPRs); region->LDS; barrier.
// P1: om MFMA (region). barrier. P2: window regs->LDS (region dead) || params. barrier.
// P4: K-split gather -> MFMA. P5: f16 merge.
__global__ __launch_bounds__(256) void k_dcn(
    const __half* __restrict__ feat, const __half* __restrict__ offf,
    const __half* __restrict__ Waf, const __half* __restrict__ Womf,
    const float* __restrict__ bom, const float* __restrict__ bd,
    float* __restrict__ out)
{
  __shared__ __align__(16) char smem[5*36*CSTR];  // 25920B: om region, then feat window
  __shared__ __align__(16) char smem2[6912];      // soff(2304)+swgt(4608); later mbuf f16 [32][72]
  __shared__ __half som[27*36];                   // om values, padded stride 36 (1944B)
  __shared__ int sflag;
  ushort4* soff = (ushort4*)smem2;                // [32*9] window-relative byte offsets (u16)
  uint4*   swgt = (uint4*)(smem2 + 2304);         // [32*9] corner weights pre-broadcast half2
  __half*  mbuf = (__half*)smem2;                 // [32 px][72] f16 partials (after P4)

  int t = threadIdx.x;
  int blk = blockIdx.x;
  int work = (blk & 7)*640 + (blk >> 3);          // XCD-contiguous: 5 images per XCD
  int n = work >> 7;
  int pbase = (work & 127) * 32;
  int hrow = pbase >> 6, wbase = pbase & 63;
  int wv = t >> 6, lane = t & 63;
  int row = lane & 15, ks = lane >> 4;

  const char* ob = (const char*)(offf + (size_t)n*(HW*64));
  const char* fb = (const char*)(feat + (size_t)n*(HW*64));
  __half* region = (__half*)smem;
  char* sfeat = smem;

  if (t == 0) sflag = 1;

  // ---- P0a: issue feat-window loads into registers (held across P1) ----
  uint4 wreg[6];
  #pragma unroll
  for (int i = 0; i < 6; ++i) {                   // 5*36*8 = 1440 uint4 units
    int u = i*256 + t;
    uint4 v = make_uint4(0,0,0,0);
    if (u < 1440) {
      int r = u / 288;
      int rem = u - r*288;
      int ci = rem >> 3, q = rem & 7;
      int y = hrow - 2 + r, xx = wbase - 2 + ci;
      if ((unsigned)y < 64u && (unsigned)xx < 64u)
        v = *(const uint4*)(fb + (((y<<6)+xx)<<7) + q*16);
    }
    wreg[i] = v;
  }

  // ---- P0b: stage off_feat region rows hrow-1..+1, cols wbase-1..+32 ----
  for (int u = t; u < 816; u += 256) {            // 3*34*8 uint4 units
    int ry = u / 272;
    int rem = u - ry*272;
    int rx = rem >> 3, q = rem & 7;
    int y = hrow + ry - 1, xx = wbase + rx - 1;
    uint4 v = make_uint4(0,0,0,0);
    if ((unsigned)y < 64u && (unsigned)xx < 64u)
      v = *(const uint4*)(ob + (((y<<6)+xx)<<7) + q*16);
    *(uint4*)((char*)region + ((ry*34 + rx)*RSTR + q*8)*2) = v;
  }
  __syncthreads();

  // ---- P1: om head via MFMA from region; frag-coalesced A ----
  {
    int mt = wv >> 1, nt = wv & 1;
    int pxl = nt*16 + row;
    f32x4 acc = {0.f,0.f,0.f,0.f};
    #pragma unroll
    for (int k0 = 0; k0 < 18; ++k0) {
      int k = k0 >> 1, ky = k/3, kx = k - ky*3;
      int c0 = (k0 & 1)*32;
      f16x8 a = *(const f16x8*)(Womf + ((mt*18 + k0)<<9) + lane*8);
      f16x8 b = *(const f16x8*)(region + (ky*34 + pxl + kx)*RSTR + c0 + ks*8);
      acc = __builtin_amdgcn_mfma_f32_16x16x32_f16(a, b, acc, 0, 0, 0);
    }
    #pragma unroll
    for (int j = 0; j < 4; ++j) {
      int oc = mt*16 + ks*4 + j;
      if (oc < 27) {
        float r = acc[j] + bom[oc];
        if (oc >= 18) r = 1.f/(1.f + __expf(-r));
        som[oc*36 + pxl] = __float2half(r);
      }
    }
  }
  __syncthreads();                                // region reads done; som visible

  // ---- P2a: write held window regs -> LDS (overwrites region) ----
  #pragma unroll
  for (int i = 0; i < 6; ++i) {
    int u = i*256 + t;
    if (u < 1440) {
      int r = u / 288;
      int rem = u - r*288;
      int ci = rem >> 3, q = rem & 7;
      *(uint4*)(sfeat + (r*36 + ci)*CSTR + q*16) = wreg[i];
    }
  }

  // ---- P2b: params -> soff/swgt (window-relative) + block flag ----
  for (int e = t; e < 32*9; e += 256) {
    int px = e / 9, k = e - px*9;
    int w = wbase + px;
    float dy = __half2float(som[(2*k)*36 + px]);
    float dx = __half2float(som[(2*k+1)*36 + px]);
    float m  = __half2float(som[(18+k)*36 + px]);
    float py = (float)(hrow + (k/3) - 1) + dy;
    float qx = (float)(w + (k - (k/3)*3) - 1) + dx;
    float y0f = floorf(py), x0f = floorf(qx);
    float wy = py - y0f, wx = qx - x0f;
    int y0 = (int)y0f, x0 = (int)x0f;
    int y1 = y0 + 1, x1 = x0 + 1;
    float w00 = (1.f-wy)*(1.f-wx)*m;
    float w01 = (1.f-wy)*wx*m;
    float w10 = wy*(1.f-wx)*m;
    float w11 = wy*wx*m;
    if (y0 < 0 || y0 >= HH) { w00 = 0.f; w01 = 0.f; }
    if (y1 < 0 || y1 >= HH) { w10 = 0.f; w11 = 0.f; }
    if (x0 < 0 || x0 >= WW) { w00 = 0.f; w10 = 0.f; }
    if (x1 < 0 || x1 >= WW) { w01 = 0.f; w11 = 0.f; }
    int y0c = min(max(y0,0),HH-1), y1c = min(max(y1,0),HH-1);
    int x0c = min(max(x0,0),WW-1), x1c = min(max(x1,0),WW-1);
    int yw0 = y0c - (hrow-2), yw1 = y1c - (hrow-2);
    int xw0 = x0c - (wbase-2), xw1 = x1c - (wbase-2);
    bool ok = ((unsigned)yw0 < 5u) & ((unsigned)yw1 < 5u)
            & ((unsigned)xw0 < 36u) & ((unsigned)xw1 < 36u);
    if (!ok) atomicAnd(&sflag, 0);
    int cy0 = min(max(yw0,0),4), cy1 = min(max(yw1,0),4);
    int cx0 = min(max(xw0,0),35), cx1 = min(max(xw1,0),35);
    soff[e] = make_ushort4((ushort)((cy0*36 + cx0)*CSTR), (ushort)((cy0*36 + cx1)*CSTR),
                           (ushort)((cy1*36 + cx0)*CSTR), (ushort)((cy1*36 + cx1)*CSTR));
    U32H2 u00, u01, u10, u11;
    u00.h = __float2half2_rn(w00); u01.h = __float2half2_rn(w01);
    u10.h = __float2half2_rn(w10); u11.h = __float2half2_rn(w11);
    swgt[e] = make_uint4(u00.u, u01.u, u10.u, u11.u);
  }
  __syncthreads();

  // ---- P4: 9 taps, K-split gather -> MFMA; wave = (nt px-tile, kg chan-half) ----
  int nt = wv & 1, kg = wv >> 1;
  int pxl = nt*16 + row;
  int cb = kg*64 + ks*16;                         // byte offset of this lane's chan slice
  f32x4 acc0 = {0.f,0.f,0.f,0.f}, acc1 = {0.f,0.f,0.f,0.f};
  f32x4 acc2 = {0.f,0.f,0.f,0.f}, acc3 = {0.f,0.f,0.f,0.f};
  const __half* afrag = Waf + (kg*9)*2048 + lane*8;   // per-tap stride 2048 halves

  if (sflag) {
    // fast path: branch-free LDS gather, fully unrolled
    #pragma unroll
    for (int tap = 0; tap < 9; ++tap) {
      int e = pxl*9 + tap;
      ushort4 off = soff[e];
      uint4 wq  = swgt[e];
      U32H2 W00, W01, W10, W11;
      W00.u = wq.x; W01.u = wq.y; W10.u = wq.z; W11.u = wq.w;
      uint4 c00 = *(const uint4*)(sfeat + (int)off.x + cb);
      uint4 c01 = *(const uint4*)(sfeat + (int)off.y + cb);
      uint4 c10 = *(const uint4*)(sfeat + (int)off.z + cb);
      uint4 c11 = *(const uint4*)(sfeat + (int)off.w + cb);
      uint4 r;
#define BILIN(comp) { U32H2 a0v,a1v,a2v,a3v,res;                                \
      a0v.u = c00.comp; a1v.u = c01.comp; a2v.u = c10.comp; a3v.u = c11.comp;   \
      __half2 v = __hmul2(W00.h, a0v.h); v = __hfma2(W01.h, a1v.h, v);          \
      v = __hfma2(W10.h, a2v.h, v);      v = __hfma2(W11.h, a3v.h, v);          \
      res.h = v; r.comp = res.u; }
      BILIN(x) BILIN(y) BILIN(z) BILIN(w)
      f16x8 b = *(f16x8*)&r;
      const __half* ap = afrag + tap*2048;
      f16x8 a0 = *(const f16x8*)(ap);
      f16x8 a1 = *(const f16x8*)(ap + 512);
      f16x8 a2 = *(const f16x8*)(ap + 1024);
      f16x8 a3 = *(const f16x8*)(ap + 1536);
      acc0 = __builtin_amdgcn_mfma_f32_16x16x32_f16(a0, b, acc0, 0, 0, 0);
      acc1 = __builtin_amdgcn_mfma_f32_16x16x32_f16(a1, b, acc1, 0, 0, 0);
      acc2 = __builtin_amdgcn_mfma_f32_16x16x32_f16(a2, b, acc2, 0, 0, 0);
      acc3 = __builtin_amdgcn_mfma_f32_16x16x32_f16(a3, b, acc3, 0, 0, 0);
    }
  } else {
    // slow path (rare): per-lane recompute, clamped global gather, branch-free
    #pragma unroll 1
    for (int tap = 0; tap < 9; ++tap) {
      float dy = __half2float(som[(2*tap)*36 + pxl]);
      float dx = __half2float(som[(2*tap+1)*36 + pxl]);
      float m  = __half2float(som[(18+tap)*36 + pxl]);
      int ky = tap/3, kx = tap - ky*3;
      float py = (float)(hrow + ky - 1) + dy;
      float qx = (float)(wbase + pxl + kx - 1) + dx;
      float y0f = floorf(py), x0f = floorf(qx);
      float wy = py - y0f, wx = qx - x0f;
      int y0 = (int)y0f, x0 = (int)x0f;
      int y1 = y0 + 1, x1 = x0 + 1;
      float w00 = (1.f-wy)*(1.f-wx)*m;
      float w01 = (1.f-wy)*wx*m;
      float w10 = wy*(1.f-wx)*m;
      float w11 = wy*wx*m;
      if (y0 < 0 || y0 >= HH) { w00 = 0.f; w01 = 0.f; }
      if (y1 < 0 || y1 >= HH) { w10 = 0.f; w11 = 0.f; }
      if (x0 < 0 || x0 >= WW) { w00 = 0.f; w10 = 0.f; }
      if (x1 < 0 || x1 >= WW) { w01 = 0.f; w11 = 0.f; }
      int y0c = min(max(y0,0),HH-1), y1c = min(max(y1,0),HH-1);
      int x0c = min(max(x0,0),WW-1), x1c = min(max(x1,0),WW-1);
      int o00 = (((y0c<<6)+x0c)<<7), o01 = (((y0c<<6)+x1c)<<7);
      int o10 = (((y1c<<6)+x0c)<<7), o11 = (((y1c<<6)+x1c)<<7);
      U32H2 W00, W01, W10, W11;
      W00.h = __float2half2_rn(w00); W01.h = __float2half2_rn(w01);
      W10.h = __float2half2_rn(w10); W11.h = __float2half2_rn(w11);
      uint4 c00 = *(const uint4*)(fb + o00 + cb);
      uint4 c01 = *(const uint4*)(fb + o01 + cb);
      uint4 c10 = *(const uint4*)(fb + o10 + cb);
      uint4 c11 = *(const uint4*)(fb + o11 + cb);
      uint4 r;
      BILIN(x) BILIN(y) BILIN(z) BILIN(w)
#undef BILIN
      f16x8 b = *(f16x8*)&r;
      const __half* ap = afrag + tap*2048;
      f16x8 a0 = *(const f16x8*)(ap);
      f16x8 a1 = *(const f16x8*)(ap + 512);
      f16x8 a2 = *(const f16x8*)(ap + 1024);
      f16x8 a3 = *(const f16x8*)(ap + 1536);
      acc0 = __builtin_amdgcn_mfma_f32_16x16x32_f16(a0, b, acc0, 0, 0, 0);
      acc1 = __builtin_amdgcn_mfma_f32_16x16x32_f16(a1, b, acc1, 0, 0, 0);
      acc2 = __builtin_amdgcn_mfma_f32_16x16x32_f16(a2, b, acc2, 0, 0, 0);
      acc3 = __builtin_amdgcn_mfma_f32_16x16x32_f16(a3, b, acc3, 0, 0, 0);
    }
  }
  __syncthreads();                                 // soff/swgt dead; mbuf live

  // ---- P5: merge K-halves (f16 partials), epilogue ----
  if (kg == 1) {
    int mb = pxl*72 + ks*4;                        // halves; stride 144B -> bank-spread
    *(ushort4*)(mbuf + mb)      = f4_to_h4(acc0);
    *(ushort4*)(mbuf + mb + 16) = f4_to_h4(acc1);
    *(ushort4*)(mbuf + mb + 32) = f4_to_h4(acc2);
    *(ushort4*)(mbuf + mb + 48) = f4_to_h4(acc3);
  }
  __syncthreads();
  if (kg == 0) {
    int mb = pxl*72 + ks*4;
    h4_add(acc0, *(ushort4*)(mbuf + mb));
    h4_add(acc1, *(ushort4*)(mbuf + mb + 16));
    h4_add(acc2, *(ushort4*)(mbuf + mb + 32));
    h4_add(acc3, *(ushort4*)(mbuf + mb + 48));
    int p = pbase + pxl;
    float* op = out + (size_t)n*(64*HW) + p;
    #pragma unroll
    for (int j = 0; j < 4; ++j) {
      int oc = ks*4 + j;
      op[(oc     )*HW] = acc0[j] + bd[oc];
      op[(oc + 16)*HW] = acc1[j] + bd[oc + 16];
      op[(oc + 32)*HW] = acc2[j] + bd[oc + 32];
      op[(oc + 48)*HW] = acc3[j] + bd[oc + 48];
    }
  }
}

// ---------------- launcher ----------------
extern "C" void kernel_launch(void* const* d_in, const int* in_sizes, int n_in,
                              void* d_out, int out_size, void* d_ws, size_t ws_size,
                              hipStream_t stream)
{
  const float* x   = (const float*)d_in[0];
  const float* Wi  = (const float*)d_in[2];
  const float* bi  = (const float*)d_in[3];
  const float* ai  = (const float*)d_in[4];
  const float* Wo  = (const float*)d_in[5];
  const float* bo  = (const float*)d_in[6];
  const float* aof = (const float*)d_in[7];
  const float* Wom = (const float*)d_in[8];
  const float* bom = (const float*)d_in[9];
  const float* Wd  = (const float*)d_in[10];
  const float* bd  = (const float*)d_in[11];
  float* out = (float*)d_out;

  __half* feat = (__half*)d_ws;
  __half* offf = feat + (size_t)NIMG*HW*64;
  __half* Waf  = offf + (size_t)NIMG*HW*64;
  __half* Womf = Waf + 36864;
  __half* Wff  = Womf + 18432;
  __half* Wof  = Wff + 2048;

  hipLaunchKernelGGL(k_wprep, dim3(240),         dim3(256), 0, stream,
                     Wd, Wom, Wi, Wo, Waf, Womf, Wff, Wof);
  hipLaunchKernelGGL(k_front, dim3(NIMG*HW/32),  dim3(256), 0, stream,
                     x, Wff, Wof, bi, ai, bo, aof, feat, offf);
  hipLaunchKernelGGL(k_dcn,   dim3(NIMG*HW/32),  dim3(256), 0, stream,
                     feat, offf, Waf, Womf, bom, bd, out);
}